// Round 6
// baseline (169.233 us; speedup 1.0000x reference)
//
#include <hip/hip_runtime.h>
#include <hip/hip_bf16.h>

// Laplace attention: N=2, C=512, S=256, fp32.
// weights[n,c,d] = softmax_d( -sum_s |k[n,d,s]-q[n,c,s]| / 2 )
// out[n,c,s] = sum_d weights[n,c,d] * v[n,d,s]
//
// Round-6: TC=4, DSPLIT=8 -> 2048 blocks (24 waves/CU at launch_bounds(256,6)).
// No accs-LDS stage: each wave writes its partial o directly to workspace
// (32 partials per output row = DSPLIT * NW; all NW partials of one half
// share that half's (m,l)). Rotating register prefetch on k and v loads.
// LDS = 1 KB (logits only).

constexpr int N_ = 2;
constexpr int C_ = 512;
constexpr int S_ = 256;
constexpr int TC = 4;             // q-rows per block
constexpr int NW = 4;             // waves per block
constexpr int DSPLIT = 8;
constexpr int DH  = C_ / DSPLIT;  // 64 d-rows per block
constexpr int DPW = DH / NW;      // 16 d-rows per wave
constexpr int NPART = DSPLIT * NW;  // 32 o-partials per output row

constexpr size_t PO_SZ = (size_t)N_ * C_ * NPART * S_;   // 8.4M floats
constexpr size_t ST_SZ = (size_t)N_ * C_ * DSPLIT;       // m/l partials

// DPP helpers: ctrl/row_mask are template params (must be constants).
template <int CTRL, int ROW_MASK>
__device__ __forceinline__ float dpp_add(float x) {
    int yi = __builtin_amdgcn_update_dpp(0, __float_as_int(x), CTRL, ROW_MASK, 0xf, true);
    return x + __int_as_float(yi);
}
template <int CTRL, int ROW_MASK>
__device__ __forceinline__ float dpp_max(float x) {
    int yi = __builtin_amdgcn_update_dpp(__float_as_int(x), __float_as_int(x), CTRL, ROW_MASK, 0xf, false);
    return fmaxf(x, __int_as_float(yi));
}
// After this: lane31 = sum(lanes 0..31), lane63 = sum(lanes 32..63).
__device__ __forceinline__ float dpp_reduce_halves(float x) {
    x = dpp_add<0x111, 0xf>(x);   // row_shr:1
    x = dpp_add<0x112, 0xf>(x);   // row_shr:2
    x = dpp_add<0x114, 0xf>(x);   // row_shr:4
    x = dpp_add<0x118, 0xf>(x);   // row_shr:8
    x = dpp_add<0x142, 0xa>(x);   // row_bcast15 into rows 1,3
    return x;
}
__device__ __forceinline__ float wave_sum_bcast(float x) {
    x = dpp_reduce_halves(x);
    x = dpp_add<0x143, 0xc>(x);   // row_bcast31 -> lane63 = total
    return __int_as_float(__builtin_amdgcn_readlane(__float_as_int(x), 63));
}
__device__ __forceinline__ float wave_max_bcast(float x) {
    x = dpp_max<0x111, 0xf>(x);
    x = dpp_max<0x112, 0xf>(x);
    x = dpp_max<0x114, 0xf>(x);
    x = dpp_max<0x118, 0xf>(x);
    x = dpp_max<0x142, 0xa>(x);
    x = dpp_max<0x143, 0xc>(x);
    return __int_as_float(__builtin_amdgcn_readlane(__float_as_int(x), 63));
}

__global__ __launch_bounds__(256, 6)
void laplace_attn_main(const float* __restrict__ q,
                       const float* __restrict__ k,
                       const float* __restrict__ v,
                       float* __restrict__ ws) {
    constexpr int per_n = (C_ / TC) * DSPLIT;   // 1024
    const int b    = blockIdx.x;                // 0..2047
    const int n    = b / per_n;
    const int r    = b - n * per_n;
    const int half = r % DSPLIT;
    const int c0   = (r / DSPLIT) * TC;
    const int tid  = threadIdx.x;
    const int w    = tid >> 6;
    const int lane = tid & 63;

    const float* kbase = k + (size_t)n * C_ * S_;
    const float* vbase = v + (size_t)n * C_ * S_;

    float* po = ws;                   // [N*C][NPART][S]
    float* pm = ws + PO_SZ;           // [N*C][DSPLIT]
    float* pl = pm + ST_SZ;           // [N*C][DSPLIT]

    __shared__ float4 wt[DH];         // per d: logits->exp for c0..c0+3 (1 KB)

    // ---- q octets in registers: lane serves row-half h, s-octet j ----
    const int h = lane >> 5;
    const int j = lane & 31;
    float4 qa[TC], qb[TC];
    #pragma unroll
    for (int c = 0; c < TC; ++c) {
        const float4* qr = (const float4*)(q + ((size_t)n * C_ + c0 + c) * S_);
        qa[c] = qr[2 * j];
        qb[c] = qr[2 * j + 1];
    }

    const int dw0 = half * DH + w * DPW;      // first global d-row for this wave

    // ---- phase 2: logits, 2 k-rows per pass, rotating prefetch ----
    {
        const float4* rp = (const float4*)(kbase + (size_t)(dw0 + h) * S_) + 2 * j;
        float4 ka = rp[0];
        float4 kb = rp[1];
        #pragma unroll
        for (int g2 = 0; g2 < DPW; g2 += 2) {
            // prefetch next pass (clamped: last pass re-reads current, L1-hot)
            const float4* rpn = (g2 + 2 < DPW) ? rp + 2 * (S_ / 4) : rp;
            float4 kan = rpn[0];
            float4 kbn = rpn[1];

            float vals[TC];
            #pragma unroll
            for (int c = 0; c < TC; ++c) {
                float p = fabsf(ka.x - qa[c].x) + fabsf(ka.y - qa[c].y)
                        + fabsf(ka.z - qa[c].z) + fabsf(ka.w - qa[c].w)
                        + fabsf(kb.x - qb[c].x) + fabsf(kb.y - qb[c].y)
                        + fabsf(kb.z - qb[c].z) + fabsf(kb.w - qb[c].w);
                vals[c] = dpp_reduce_halves(p);   // lane31/63 = the 2 row sums
            }
            if ((lane & 31) == 31) {              // lanes 31,63 write their row
                wt[w * DPW + g2 + h] = make_float4(-0.5f * vals[0], -0.5f * vals[1],
                                                   -0.5f * vals[2], -0.5f * vals[3]);
            }
            ka = kan; kb = kbn; rp = rpn;
        }
    }
    __syncthreads();

    // ---- softmax (partial, unnormalized): wave w handles c = w ----
    {
        float* wtf = (float*)wt;                  // [DH][TC]
        const float x = wtf[lane * TC + w];       // one logit per lane (DH=64)
        const float m = wave_max_bcast(x);
        const float e = __expf(x - m);
        const float l = wave_sum_bcast(e);
        wtf[lane * TC + w] = e;
        if (lane == 0) {
            const size_t sidx = ((size_t)n * C_ + c0 + w) * DSPLIT + half;
            pm[sidx] = m;
            pl[sidx] = l;
        }
    }
    __syncthreads();

    // ---- phase 4: per-wave partial o over its DPW rows, prefetched ----
    float4 acc[TC];
    #pragma unroll
    for (int c = 0; c < TC; ++c) acc[c] = make_float4(0.f, 0.f, 0.f, 0.f);

    {
        const float4* vp = (const float4*)(vbase + (size_t)dw0 * S_) + lane;
        float4 vv = vp[0];
        #pragma unroll
        for (int dd = 0; dd < DPW; ++dd) {
            const float4* vpn = (dd + 1 < DPW) ? vp + (S_ / 4) : vp;
            float4 vvn = vpn[0];
            const float4 ww = wt[w * DPW + dd];   // uniform b128 broadcast
            acc[0].x += ww.x * vv.x; acc[0].y += ww.x * vv.y;
            acc[0].z += ww.x * vv.z; acc[0].w += ww.x * vv.w;
            acc[1].x += ww.y * vv.x; acc[1].y += ww.y * vv.y;
            acc[1].z += ww.y * vv.z; acc[1].w += ww.y * vv.w;
            acc[2].x += ww.z * vv.x; acc[2].y += ww.z * vv.y;
            acc[2].z += ww.z * vv.z; acc[2].w += ww.z * vv.w;
            acc[3].x += ww.w * vv.x; acc[3].y += ww.w * vv.y;
            acc[3].z += ww.w * vv.z; acc[3].w += ww.w * vv.w;
            vv = vvn; vp = vpn;
        }
    }

    // ---- epilogue: write per-wave partials directly (coalesced) ----
    #pragma unroll
    for (int c = 0; c < TC; ++c) {
        const size_t row  = (size_t)n * C_ + c0 + c;
        const size_t oidx = ((row * DSPLIT + half) * NW + w) * S_;
        ((float4*)(po + oidx))[lane] = acc[c];
    }
}

__global__ __launch_bounds__(64)
void laplace_attn_combine(const float* __restrict__ ws,
                          float* __restrict__ out) {
    const int b    = blockIdx.x;      // (n*C + c), 0..1023
    const int lane = threadIdx.x;     // s-quad

    const float* po = ws;
    const float* pm = ws + PO_SZ;
    const float* pl = pm + ST_SZ;

    float m[DSPLIT], l[DSPLIT];
    #pragma unroll
    for (int hh = 0; hh < DSPLIT; ++hh) {
        m[hh] = pm[(size_t)b * DSPLIT + hh];
        l[hh] = pl[(size_t)b * DSPLIT + hh];
    }
    float M = m[0];
    #pragma unroll
    for (int hh = 1; hh < DSPLIT; ++hh) M = fmaxf(M, m[hh]);
    float den = 0.f, a[DSPLIT];
    #pragma unroll
    for (int hh = 0; hh < DSPLIT; ++hh) { a[hh] = __expf(m[hh] - M); den += a[hh] * l[hh]; }
    const float inv = 1.f / den;

    float4 rsum = make_float4(0.f, 0.f, 0.f, 0.f);
    #pragma unroll
    for (int p2 = 0; p2 < NPART; ++p2) {
        const float wgt = a[p2 / NW];     // partial p2 belongs to half p2/NW
        const float4 o = ((const float4*)(po + ((size_t)b * NPART + p2) * S_))[lane];
        rsum.x += wgt * o.x;
        rsum.y += wgt * o.y;
        rsum.z += wgt * o.z;
        rsum.w += wgt * o.w;
    }
    float4 rr;
    rr.x = rsum.x * inv; rr.y = rsum.y * inv;
    rr.z = rsum.z * inv; rr.w = rsum.w * inv;
    ((float4*)(out + (size_t)b * S_))[lane] = rr;
}

extern "C" void kernel_launch(void* const* d_in, const int* in_sizes, int n_in,
                              void* d_out, int out_size, void* d_ws, size_t ws_size,
                              hipStream_t stream) {
    const float* q = (const float*)d_in[0];
    const float* k = (const float*)d_in[1];
    const float* v = (const float*)d_in[2];
    float* out = (float*)d_out;
    float* ws  = (float*)d_ws;

    laplace_attn_main<<<dim3(N_ * (C_ / TC) * DSPLIT), dim3(256), 0, stream>>>(q, k, v, ws);
    laplace_attn_combine<<<dim3(N_ * C_), dim3(64), 0, stream>>>(ws, out);
}

// Round 7
// 84.910 us; speedup vs baseline: 1.9931x; 1.9931x over previous
//
#include <hip/hip_runtime.h>
#include <hip/hip_bf16.h>

// Laplace attention: N=2, C=512, S=256, fp32.
// weights[n,c,d] = softmax_d( -sum_s |k[n,d,s]-q[n,c,s]| / 2 )
// out[n,c,s] = sum_d weights[n,c,d] * v[n,d,s]
//
// Round-7: TC=4, DSPLIT=8, NW=4 -> 2048 blocks = 8 blocks/CU = 32 waves/CU.
// Block-level LDS combine of the 4 waves' o-partials (round-6's per-wave
// direct-to-ws partials made po 33.5 MB and thrashed L2: FETCH 114 MB,
// WRITE 228 MB, 3.3 TB/s memory-bound). po here = 8.4 MB, L2-resident.
// Rotating register prefetch on k and v; lanes 31/63 write logits directly.

constexpr int N_ = 2;
constexpr int C_ = 512;
constexpr int S_ = 256;
constexpr int TC = 4;             // q-rows per block
constexpr int NW = 4;             // waves per block
constexpr int DSPLIT = 8;
constexpr int DH  = C_ / DSPLIT;  // 64 d-rows per block
constexpr int DPW = DH / NW;      // 16 d-rows per wave

constexpr size_t PO_SZ = (size_t)N_ * C_ * DSPLIT * S_;  // 2.1M floats, 8.4 MB
constexpr size_t ST_SZ = (size_t)N_ * C_ * DSPLIT;       // m/l partials

// DPP helpers: ctrl/row_mask are template params (must be constants).
template <int CTRL, int ROW_MASK>
__device__ __forceinline__ float dpp_add(float x) {
    int yi = __builtin_amdgcn_update_dpp(0, __float_as_int(x), CTRL, ROW_MASK, 0xf, true);
    return x + __int_as_float(yi);
}
template <int CTRL, int ROW_MASK>
__device__ __forceinline__ float dpp_max(float x) {
    int yi = __builtin_amdgcn_update_dpp(__float_as_int(x), __float_as_int(x), CTRL, ROW_MASK, 0xf, false);
    return fmaxf(x, __int_as_float(yi));
}
// After this: lane31 = sum(lanes 0..31), lane63 = sum(lanes 32..63).
__device__ __forceinline__ float dpp_reduce_halves(float x) {
    x = dpp_add<0x111, 0xf>(x);   // row_shr:1
    x = dpp_add<0x112, 0xf>(x);   // row_shr:2
    x = dpp_add<0x114, 0xf>(x);   // row_shr:4
    x = dpp_add<0x118, 0xf>(x);   // row_shr:8
    x = dpp_add<0x142, 0xa>(x);   // row_bcast15 into rows 1,3
    return x;
}
__device__ __forceinline__ float wave_sum_bcast(float x) {
    x = dpp_reduce_halves(x);
    x = dpp_add<0x143, 0xc>(x);   // row_bcast31 -> lane63 = total
    return __int_as_float(__builtin_amdgcn_readlane(__float_as_int(x), 63));
}
__device__ __forceinline__ float wave_max_bcast(float x) {
    x = dpp_max<0x111, 0xf>(x);
    x = dpp_max<0x112, 0xf>(x);
    x = dpp_max<0x114, 0xf>(x);
    x = dpp_max<0x118, 0xf>(x);
    x = dpp_max<0x142, 0xa>(x);
    x = dpp_max<0x143, 0xc>(x);
    return __int_as_float(__builtin_amdgcn_readlane(__float_as_int(x), 63));
}

__global__ __launch_bounds__(256, 8)
void laplace_attn_main(const float* __restrict__ q,
                       const float* __restrict__ k,
                       const float* __restrict__ v,
                       float* __restrict__ ws) {
    constexpr int per_n = (C_ / TC) * DSPLIT;   // 1024
    const int b    = blockIdx.x;                // 0..2047
    const int n    = b / per_n;
    const int r    = b - n * per_n;
    const int half = r % DSPLIT;
    const int c0   = (r / DSPLIT) * TC;
    const int tid  = threadIdx.x;
    const int w    = tid >> 6;
    const int lane = tid & 63;

    const float* kbase = k + (size_t)n * C_ * S_;
    const float* vbase = v + (size_t)n * C_ * S_;

    float* po = ws;                   // [N*C][DSPLIT][S]
    float* pm = ws + PO_SZ;           // [N*C][DSPLIT]
    float* pl = pm + ST_SZ;           // [N*C][DSPLIT]

    __shared__ float4 wt[DH];               // logits->exp for c0..c0+3 (1 KB)
    __shared__ float4 accs[NW][TC][64];     // per-wave o partials (16 KB)

    // ---- q octets in registers: lane serves row-half h, s-octet j ----
    const int h = lane >> 5;
    const int j = lane & 31;
    float4 qa[TC], qb[TC];
    #pragma unroll
    for (int c = 0; c < TC; ++c) {
        const float4* qr = (const float4*)(q + ((size_t)n * C_ + c0 + c) * S_);
        qa[c] = qr[2 * j];
        qb[c] = qr[2 * j + 1];
    }

    const int dw0 = half * DH + w * DPW;    // first global d-row for this wave

    // ---- phase 2: logits, 2 k-rows per pass, rotating prefetch ----
    {
        const float4* rp = (const float4*)(kbase + (size_t)(dw0 + h) * S_) + 2 * j;
        float4 ka = rp[0];
        float4 kb = rp[1];
        #pragma unroll
        for (int g2 = 0; g2 < DPW; g2 += 2) {
            // prefetch next pass (clamped: last pass re-reads current, L1-hot)
            const float4* rpn = (g2 + 2 < DPW) ? rp + 2 * (S_ / 4) : rp;
            float4 kan = rpn[0];
            float4 kbn = rpn[1];

            float vals[TC];
            #pragma unroll
            for (int c = 0; c < TC; ++c) {
                float p = fabsf(ka.x - qa[c].x) + fabsf(ka.y - qa[c].y)
                        + fabsf(ka.z - qa[c].z) + fabsf(ka.w - qa[c].w)
                        + fabsf(kb.x - qb[c].x) + fabsf(kb.y - qb[c].y)
                        + fabsf(kb.z - qb[c].z) + fabsf(kb.w - qb[c].w);
                vals[c] = dpp_reduce_halves(p);   // lane31/63 = the 2 row sums
            }
            if ((lane & 31) == 31) {              // lanes 31,63 write their row
                wt[w * DPW + g2 + h] = make_float4(-0.5f * vals[0], -0.5f * vals[1],
                                                   -0.5f * vals[2], -0.5f * vals[3]);
            }
            ka = kan; kb = kbn; rp = rpn;
        }
    }
    __syncthreads();

    // ---- softmax (partial, unnormalized): wave w handles c = w ----
    {
        float* wtf = (float*)wt;                  // [DH][TC]
        const float x = wtf[lane * TC + w];       // one logit per lane (DH=64)
        const float m = wave_max_bcast(x);
        const float e = __expf(x - m);
        const float l = wave_sum_bcast(e);
        wtf[lane * TC + w] = e;
        if (lane == 0) {
            const size_t sidx = ((size_t)n * C_ + c0 + w) * DSPLIT + half;
            pm[sidx] = m;
            pl[sidx] = l;
        }
    }
    __syncthreads();

    // ---- phase 4: per-wave partial o over its DPW rows, prefetched ----
    float4 acc[TC];
    #pragma unroll
    for (int c = 0; c < TC; ++c) acc[c] = make_float4(0.f, 0.f, 0.f, 0.f);

    {
        const float4* vp = (const float4*)(vbase + (size_t)dw0 * S_) + lane;
        float4 vv = vp[0];
        #pragma unroll
        for (int dd = 0; dd < DPW; ++dd) {
            const float4* vpn = (dd + 1 < DPW) ? vp + (S_ / 4) : vp;
            float4 vvn = vpn[0];
            const float4 ww = wt[w * DPW + dd];   // uniform b128 broadcast
            acc[0].x += ww.x * vv.x; acc[0].y += ww.x * vv.y;
            acc[0].z += ww.x * vv.z; acc[0].w += ww.x * vv.w;
            acc[1].x += ww.y * vv.x; acc[1].y += ww.y * vv.y;
            acc[1].z += ww.y * vv.z; acc[1].w += ww.y * vv.w;
            acc[2].x += ww.z * vv.x; acc[2].y += ww.z * vv.y;
            acc[2].z += ww.z * vv.z; acc[2].w += ww.z * vv.w;
            acc[3].x += ww.w * vv.x; acc[3].y += ww.w * vv.y;
            acc[3].z += ww.w * vv.z; acc[3].w += ww.w * vv.w;
            vv = vvn; vp = vpn;
        }
    }
    #pragma unroll
    for (int c = 0; c < TC; ++c) accs[w][c][lane] = acc[c];
    __syncthreads();

    // ---- epilogue: combine the 4 waves' partials, write workspace ----
    {
        const int c = w;                          // wave w writes row c0+w
        const float4 a0 = accs[0][c][lane];
        const float4 a1 = accs[1][c][lane];
        const float4 a2 = accs[2][c][lane];
        const float4 a3 = accs[3][c][lane];
        float4 o;
        o.x = (a0.x + a1.x) + (a2.x + a3.x);
        o.y = (a0.y + a1.y) + (a2.y + a3.y);
        o.z = (a0.z + a1.z) + (a2.z + a3.z);
        o.w = (a0.w + a1.w) + (a2.w + a3.w);
        const size_t oidx = (((size_t)n * C_ + c0 + c) * DSPLIT + half) * S_;
        ((float4*)(po + oidx))[lane] = o;
    }
}

__global__ __launch_bounds__(64)
void laplace_attn_combine(const float* __restrict__ ws,
                          float* __restrict__ out) {
    const int b    = blockIdx.x;      // (n*C + c), 0..1023
    const int lane = threadIdx.x;     // s-quad

    const float* po = ws;
    const float* pm = ws + PO_SZ;
    const float* pl = pm + ST_SZ;

    float m[DSPLIT], l[DSPLIT];
    #pragma unroll
    for (int hh = 0; hh < DSPLIT; ++hh) {
        m[hh] = pm[(size_t)b * DSPLIT + hh];
        l[hh] = pl[(size_t)b * DSPLIT + hh];
    }
    float M = m[0];
    #pragma unroll
    for (int hh = 1; hh < DSPLIT; ++hh) M = fmaxf(M, m[hh]);
    float den = 0.f, a[DSPLIT];
    #pragma unroll
    for (int hh = 0; hh < DSPLIT; ++hh) { a[hh] = __expf(m[hh] - M); den += a[hh] * l[hh]; }
    const float inv = 1.f / den;

    float4 rsum = make_float4(0.f, 0.f, 0.f, 0.f);
    #pragma unroll
    for (int hh = 0; hh < DSPLIT; ++hh) {
        const float4 o = ((const float4*)(po + ((size_t)b * DSPLIT + hh) * S_))[lane];
        rsum.x += a[hh] * o.x;
        rsum.y += a[hh] * o.y;
        rsum.z += a[hh] * o.z;
        rsum.w += a[hh] * o.w;
    }
    float4 rr;
    rr.x = rsum.x * inv; rr.y = rsum.y * inv;
    rr.z = rsum.z * inv; rr.w = rsum.w * inv;
    ((float4*)(out + (size_t)b * S_))[lane] = rr;
}

extern "C" void kernel_launch(void* const* d_in, const int* in_sizes, int n_in,
                              void* d_out, int out_size, void* d_ws, size_t ws_size,
                              hipStream_t stream) {
    const float* q = (const float*)d_in[0];
    const float* k = (const float*)d_in[1];
    const float* v = (const float*)d_in[2];
    float* out = (float*)d_out;
    float* ws  = (float*)d_ws;

    laplace_attn_main<<<dim3(N_ * (C_ / TC) * DSPLIT), dim3(256), 0, stream>>>(q, k, v, ws);
    laplace_attn_combine<<<dim3(N_ * C_), dim3(64), 0, stream>>>(ws, out);
}

// Round 8
// 79.376 us; speedup vs baseline: 2.1320x; 1.0697x over previous
//
#include <hip/hip_runtime.h>
#include <hip/hip_bf16.h>

// Laplace attention: N=2, C=512, S=256, fp32.
// weights[n,c,d] = softmax_d( -sum_s |k[n,d,s]-q[n,c,s]| / 2 )
// out[n,c,s] = sum_d weights[n,c,d] * v[n,d,s]
//
// Round-8: exact round-4 skeleton (best: 77.3 us total; TC=4, DSPLIT=4,
// NW=4, 1024 blocks, accs-LDS combine) + ONE change: depth-2 rotating
// register prefetch on the k-loop and v-loop. r4 exposed ~200cyc L2 latency
// per 2-pass group against ~160cyc of issue; depth-2 keeps ~320cyc in flight.

constexpr int N_ = 2;
constexpr int C_ = 512;
constexpr int S_ = 256;
constexpr int TC = 4;             // q-rows per block
constexpr int NW = 4;             // waves per block
constexpr int DSPLIT = 4;
constexpr int DH  = C_ / DSPLIT;  // 128 d-rows per block
constexpr int DPW = DH / NW;      // 32 d-rows per wave
constexpr int NPASS = DPW / 2;    // 16 two-row passes per wave

constexpr size_t PO_SZ = (size_t)N_ * C_ * DSPLIT * S_;  // 4 MB of partials
constexpr size_t ST_SZ = (size_t)N_ * C_ * DSPLIT;       // m/l partials

// DPP helpers: ctrl/row_mask are template params (must be constants).
template <int CTRL, int ROW_MASK>
__device__ __forceinline__ float dpp_add(float x) {
    int yi = __builtin_amdgcn_update_dpp(0, __float_as_int(x), CTRL, ROW_MASK, 0xf, true);
    return x + __int_as_float(yi);
}
template <int CTRL, int ROW_MASK>
__device__ __forceinline__ float dpp_max(float x) {
    int yi = __builtin_amdgcn_update_dpp(__float_as_int(x), __float_as_int(x), CTRL, ROW_MASK, 0xf, false);
    return fmaxf(x, __int_as_float(yi));
}
// After this: lane31 = sum(lanes 0..31), lane63 = sum(lanes 32..63).
__device__ __forceinline__ float dpp_reduce_halves(float x) {
    x = dpp_add<0x111, 0xf>(x);   // row_shr:1
    x = dpp_add<0x112, 0xf>(x);   // row_shr:2
    x = dpp_add<0x114, 0xf>(x);   // row_shr:4
    x = dpp_add<0x118, 0xf>(x);   // row_shr:8
    x = dpp_add<0x142, 0xa>(x);   // row_bcast15 into rows 1,3
    return x;
}
__device__ __forceinline__ float wave_sum_bcast(float x) {
    x = dpp_reduce_halves(x);
    x = dpp_add<0x143, 0xc>(x);   // row_bcast31 -> lane63 = total
    return __int_as_float(__builtin_amdgcn_readlane(__float_as_int(x), 63));
}
__device__ __forceinline__ float wave_max_bcast(float x) {
    x = dpp_max<0x111, 0xf>(x);
    x = dpp_max<0x112, 0xf>(x);
    x = dpp_max<0x114, 0xf>(x);
    x = dpp_max<0x118, 0xf>(x);
    x = dpp_max<0x142, 0xa>(x);
    x = dpp_max<0x143, 0xc>(x);
    return __int_as_float(__builtin_amdgcn_readlane(__float_as_int(x), 63));
}

__global__ __launch_bounds__(256, 4)
void laplace_attn_main(const float* __restrict__ q,
                       const float* __restrict__ k,
                       const float* __restrict__ v,
                       float* __restrict__ ws) {
    constexpr int per_n = (C_ / TC) * DSPLIT;   // 512
    const int b    = blockIdx.x;                // 0..1023
    const int n    = b / per_n;
    const int r    = b - n * per_n;
    const int half = r % DSPLIT;
    const int c0   = (r / DSPLIT) * TC;
    const int tid  = threadIdx.x;
    const int w    = tid >> 6;
    const int lane = tid & 63;

    const float* kbase = k + (size_t)n * C_ * S_;
    const float* vbase = v + (size_t)n * C_ * S_;

    float* po = ws;                   // [N*C][DSPLIT][S]
    float* pm = ws + PO_SZ;           // [N*C][DSPLIT]
    float* pl = pm + ST_SZ;           // [N*C][DSPLIT]

    __shared__ float4 wt[DH];               // logits->exp for c0..c0+3 (2 KB)
    __shared__ float4 accs[NW][TC][64];     // per-wave o partials (16 KB)

    // ---- q octets in registers: lane serves row-half h, s-octet j ----
    const int h = lane >> 5;
    const int j = lane & 31;
    float4 qa[TC], qb[TC];
    #pragma unroll
    for (int c = 0; c < TC; ++c) {
        const float4* qr = (const float4*)(q + ((size_t)n * C_ + c0 + c) * S_);
        qa[c] = qr[2 * j];
        qb[c] = qr[2 * j + 1];
    }

    const int dw0 = half * DH + w * DPW;    // first global d-row for this wave

    // ---- phase 2: logits, 2 k-rows/pass, depth-2 rotating prefetch ----
    {
        // pass p uses row dw0 + 2p + h, float4s [2j] and [2j+1]
        const float4* base = (const float4*)(kbase + (size_t)(dw0 + h) * S_) + 2 * j;
        constexpr int RSTEP = 2 * (S_ / 4);          // 2 rows in float4 units
        float4 ka0 = base[0],         kb0 = base[1];          // pass 0
        float4 ka1 = base[RSTEP],     kb1 = base[RSTEP + 1];  // pass 1

        #pragma unroll
        for (int p = 0; p < NPASS; ++p) {
            // prefetch pass p+2 (clamped; tail re-reads are L1-hot)
            const int pn = (p + 2 < NPASS) ? p + 2 : NPASS - 1;
            const float4* np = base + pn * RSTEP;
            float4 kan = np[0];
            float4 kbn = np[1];

            float vals[TC];
            #pragma unroll
            for (int c = 0; c < TC; ++c) {
                float pr = fabsf(ka0.x - qa[c].x) + fabsf(ka0.y - qa[c].y)
                         + fabsf(ka0.z - qa[c].z) + fabsf(ka0.w - qa[c].w)
                         + fabsf(kb0.x - qb[c].x) + fabsf(kb0.y - qb[c].y)
                         + fabsf(kb0.z - qb[c].z) + fabsf(kb0.w - qb[c].w);
                vals[c] = dpp_reduce_halves(pr);  // lane31/63 = the 2 row sums
            }
            if ((lane & 31) == 31) {              // lanes 31,63 write their row
                wt[w * DPW + 2 * p + h] = make_float4(-0.5f * vals[0], -0.5f * vals[1],
                                                      -0.5f * vals[2], -0.5f * vals[3]);
            }
            ka0 = ka1; kb0 = kb1;
            ka1 = kan; kb1 = kbn;
        }
    }
    __syncthreads();

    // ---- softmax (partial, unnormalized): wave w handles c = w ----
    {
        float* wtf = (float*)wt;                  // [DH][TC]
        float x0 = wtf[(lane +  0) * TC + w];     // DH=128 -> 2 elems per lane
        float x1 = wtf[(lane + 64) * TC + w];
        float m = wave_max_bcast(fmaxf(x0, x1));
        float e0 = __expf(x0 - m);
        float e1 = __expf(x1 - m);
        float l = wave_sum_bcast(e0 + e1);
        wtf[(lane +  0) * TC + w] = e0;
        wtf[(lane + 64) * TC + w] = e1;
        if (lane == 0) {
            const size_t sidx = ((size_t)n * C_ + c0 + w) * DSPLIT + half;
            pm[sidx] = m;
            pl[sidx] = l;
        }
    }
    __syncthreads();

    // ---- phase 4: per-wave partial o, depth-2 rotating prefetch ----
    float4 acc[TC];
    #pragma unroll
    for (int c = 0; c < TC; ++c) acc[c] = make_float4(0.f, 0.f, 0.f, 0.f);

    {
        const float4* vp = (const float4*)(vbase + (size_t)dw0 * S_) + lane;
        constexpr int VSTEP = S_ / 4;            // one row in float4 units
        float4 v0 = vp[0];
        float4 v1 = vp[VSTEP];
        #pragma unroll
        for (int dd = 0; dd < DPW; ++dd) {
            const int dn = (dd + 2 < DPW) ? dd + 2 : DPW - 1;
            float4 vn = vp[dn * VSTEP];
            const float4 ww = wt[w * DPW + dd];  // uniform b128 broadcast
            acc[0].x += ww.x * v0.x; acc[0].y += ww.x * v0.y;
            acc[0].z += ww.x * v0.z; acc[0].w += ww.x * v0.w;
            acc[1].x += ww.y * v0.x; acc[1].y += ww.y * v0.y;
            acc[1].z += ww.y * v0.z; acc[1].w += ww.y * v0.w;
            acc[2].x += ww.z * v0.x; acc[2].y += ww.z * v0.y;
            acc[2].z += ww.z * v0.z; acc[2].w += ww.z * v0.w;
            acc[3].x += ww.w * v0.x; acc[3].y += ww.w * v0.y;
            acc[3].z += ww.w * v0.z; acc[3].w += ww.w * v0.w;
            v0 = v1; v1 = vn;
        }
    }
    #pragma unroll
    for (int c = 0; c < TC; ++c) accs[w][c][lane] = acc[c];
    __syncthreads();

    // ---- epilogue: combine the 4 waves' partials, write workspace ----
    {
        const int c = w;                          // wave w writes row c0+w
        const float4 a0 = accs[0][c][lane];
        const float4 a1 = accs[1][c][lane];
        const float4 a2 = accs[2][c][lane];
        const float4 a3 = accs[3][c][lane];
        float4 o;
        o.x = (a0.x + a1.x) + (a2.x + a3.x);
        o.y = (a0.y + a1.y) + (a2.y + a3.y);
        o.z = (a0.z + a1.z) + (a2.z + a3.z);
        o.w = (a0.w + a1.w) + (a2.w + a3.w);
        const size_t oidx = (((size_t)n * C_ + c0 + c) * DSPLIT + half) * S_;
        ((float4*)(po + oidx))[lane] = o;
    }
}

__global__ __launch_bounds__(64)
void laplace_attn_combine(const float* __restrict__ ws,
                          float* __restrict__ out) {
    const int b    = blockIdx.x;      // (n*C + c), 0..1023
    const int lane = threadIdx.x;     // s-quad

    const float* po = ws;
    const float* pm = ws + PO_SZ;
    const float* pl = pm + ST_SZ;

    float m[DSPLIT], l[DSPLIT];
    #pragma unroll
    for (int hh = 0; hh < DSPLIT; ++hh) {
        m[hh] = pm[(size_t)b * DSPLIT + hh];
        l[hh] = pl[(size_t)b * DSPLIT + hh];
    }
    float M = m[0];
    #pragma unroll
    for (int hh = 1; hh < DSPLIT; ++hh) M = fmaxf(M, m[hh]);
    float den = 0.f, a[DSPLIT];
    #pragma unroll
    for (int hh = 0; hh < DSPLIT; ++hh) { a[hh] = __expf(m[hh] - M); den += a[hh] * l[hh]; }
    const float inv = 1.f / den;

    float4 rsum = make_float4(0.f, 0.f, 0.f, 0.f);
    #pragma unroll
    for (int hh = 0; hh < DSPLIT; ++hh) {
        const float4 o = ((const float4*)(po + ((size_t)b * DSPLIT + hh) * S_))[lane];
        rsum.x += a[hh] * o.x;
        rsum.y += a[hh] * o.y;
        rsum.z += a[hh] * o.z;
        rsum.w += a[hh] * o.w;
    }
    float4 rr;
    rr.x = rsum.x * inv; rr.y = rsum.y * inv;
    rr.z = rsum.z * inv; rr.w = rsum.w * inv;
    ((float4*)(out + (size_t)b * S_))[lane] = rr;
}

extern "C" void kernel_launch(void* const* d_in, const int* in_sizes, int n_in,
                              void* d_out, int out_size, void* d_ws, size_t ws_size,
                              hipStream_t stream) {
    const float* q = (const float*)d_in[0];
    const float* k = (const float*)d_in[1];
    const float* v = (const float*)d_in[2];
    float* out = (float*)d_out;
    float* ws  = (float*)d_ws;

    laplace_attn_main<<<dim3(N_ * (C_ / TC) * DSPLIT), dim3(256), 0, stream>>>(q, k, v, ws);
    laplace_attn_combine<<<dim3(N_ * C_), dim3(64), 0, stream>>>(ws, out);
}

// Round 9
// 78.482 us; speedup vs baseline: 2.1563x; 1.0114x over previous
//
#include <hip/hip_runtime.h>
#include <hip/hip_bf16.h>

// Laplace attention: N=2, C=512, S=256, fp32.
// weights[n,c,d] = softmax_d( -sum_s |k[n,d,s]-q[n,c,s]| / 2 )
// out[n,c,s] = sum_d weights[n,c,d] * v[n,d,s]
//
// Round-9: SINGLE fused kernel. Grid = N*(C/TC) = 256 blocks of 1024 threads
// (16 waves). Each block owns TC=4 q-rows and iterates ALL 512 d-rows:
// full softmax in-block (no flash merge, no workspace, no combine kernel).
// Phase 2 uses 4 k-rows per pass (16 lanes per row): DPP reduce is only
// 4 steps (row_shr 1/2/4/8 within 16-lane DPP rows), amortized over 4 rows.
// Normalized weights (e/l) stored in LDS; epilogue sums 16 wave-partials
// and writes d_out directly.

constexpr int N_ = 2;
constexpr int C_ = 512;
constexpr int S_ = 256;
constexpr int TC = 4;              // q-rows per block
constexpr int NW = 16;             // waves per block (1024 threads)
constexpr int DPW = C_ / NW;       // 32 d-rows per wave
constexpr int RPP = 4;             // k-rows per pass (16 lanes each)
constexpr int NPASS = DPW / RPP;   // 8 passes per wave

// DPP helpers: ctrl/row_mask are template params (must be constants).
template <int CTRL, int ROW_MASK>
__device__ __forceinline__ float dpp_add(float x) {
    int yi = __builtin_amdgcn_update_dpp(0, __float_as_int(x), CTRL, ROW_MASK, 0xf, true);
    return x + __int_as_float(yi);
}
template <int CTRL, int ROW_MASK>
__device__ __forceinline__ float dpp_max(float x) {
    int yi = __builtin_amdgcn_update_dpp(__float_as_int(x), __float_as_int(x), CTRL, ROW_MASK, 0xf, false);
    return fmaxf(x, __int_as_float(yi));
}
// Reduce within each 16-lane DPP row: lanes 15/31/47/63 hold their row's sum.
__device__ __forceinline__ float dpp_reduce16(float x) {
    x = dpp_add<0x111, 0xf>(x);   // row_shr:1
    x = dpp_add<0x112, 0xf>(x);   // row_shr:2
    x = dpp_add<0x114, 0xf>(x);   // row_shr:4
    x = dpp_add<0x118, 0xf>(x);   // row_shr:8
    return x;
}
__device__ __forceinline__ float wave_sum_bcast(float x) {
    x = dpp_reduce16(x);
    x = dpp_add<0x142, 0xa>(x);   // row_bcast15 into rows 1,3
    x = dpp_add<0x143, 0xc>(x);   // row_bcast31 -> lane63 = total
    return __int_as_float(__builtin_amdgcn_readlane(__float_as_int(x), 63));
}
__device__ __forceinline__ float wave_max_bcast(float x) {
    x = dpp_max<0x111, 0xf>(x);
    x = dpp_max<0x112, 0xf>(x);
    x = dpp_max<0x114, 0xf>(x);
    x = dpp_max<0x118, 0xf>(x);
    x = dpp_max<0x142, 0xa>(x);
    x = dpp_max<0x143, 0xc>(x);
    return __int_as_float(__builtin_amdgcn_readlane(__float_as_int(x), 63));
}

__global__ __launch_bounds__(1024, 1)
void laplace_attn_fused(const float* __restrict__ q,
                        const float* __restrict__ k,
                        const float* __restrict__ v,
                        float* __restrict__ out) {
    const int b    = blockIdx.x;               // 0..255
    const int n    = b / (C_ / TC);
    const int c0   = (b % (C_ / TC)) * TC;
    const int tid  = threadIdx.x;              // 0..1023
    const int w    = tid >> 6;                 // wave 0..15
    const int lane = tid & 63;

    const float* kbase = k + (size_t)n * C_ * S_;
    const float* vbase = v + (size_t)n * C_ * S_;

    __shared__ float4 wtq[C_];                 // per d-row: 4 c logits -> e/l (8 KB)
    __shared__ float4 accs[NW][TC][64];        // per-wave o partials (64 KB)

    // ---- q fragments: lane serves pass-row g = lane>>4, elems p = lane&15 ----
    // lane owns s = p*16 .. p*16+15 (4 float4s) of each of the TC q-rows.
    const int g = lane >> 4;
    const int p = lane & 15;
    float4 qf[TC][4];
    #pragma unroll
    for (int c = 0; c < TC; ++c) {
        const float4* qr = (const float4*)(q + ((size_t)n * C_ + c0 + c) * S_) + p * 4;
        qf[c][0] = qr[0]; qf[c][1] = qr[1]; qf[c][2] = qr[2]; qf[c][3] = qr[3];
    }

    // ---- phase 2: logits, 4 k-rows per pass ----
    #pragma unroll 2
    for (int ps = 0; ps < NPASS; ++ps) {
        const int row = w * DPW + ps * RPP + g;
        const float4* kr = (const float4*)(kbase + (size_t)row * S_) + p * 4;
        const float4 k0 = kr[0], k1 = kr[1], k2 = kr[2], k3 = kr[3];
        float vals[TC];
        #pragma unroll
        for (int c = 0; c < TC; ++c) {
            float a0 = fabsf(k0.x - qf[c][0].x) + fabsf(k0.y - qf[c][0].y)
                     + fabsf(k0.z - qf[c][0].z) + fabsf(k0.w - qf[c][0].w);
            float a1 = fabsf(k1.x - qf[c][1].x) + fabsf(k1.y - qf[c][1].y)
                     + fabsf(k1.z - qf[c][1].z) + fabsf(k1.w - qf[c][1].w);
            float a2 = fabsf(k2.x - qf[c][2].x) + fabsf(k2.y - qf[c][2].y)
                     + fabsf(k2.z - qf[c][2].z) + fabsf(k2.w - qf[c][2].w);
            float a3 = fabsf(k3.x - qf[c][3].x) + fabsf(k3.y - qf[c][3].y)
                     + fabsf(k3.z - qf[c][3].z) + fabsf(k3.w - qf[c][3].w);
            vals[c] = dpp_reduce16((a0 + a1) + (a2 + a3));
        }
        if (p == 15) {                         // lanes 15/31/47/63: one row each
            wtq[row] = make_float4(-0.5f * vals[0], -0.5f * vals[1],
                                   -0.5f * vals[2], -0.5f * vals[3]);
        }
    }
    __syncthreads();

    // ---- softmax over all 512 d (full, normalized): waves 0..3, c = w ----
    if (w < TC) {
        const int c = w;
        float* wtf = (float*)wtq;              // [C_][4]
        float x[C_ / 64];
        #pragma unroll
        for (int i = 0; i < C_ / 64; ++i) x[i] = wtf[(i * 64 + lane) * 4 + c];
        float m = x[0];
        #pragma unroll
        for (int i = 1; i < C_ / 64; ++i) m = fmaxf(m, x[i]);
        m = wave_max_bcast(m);
        float e[C_ / 64], l = 0.f;
        #pragma unroll
        for (int i = 0; i < C_ / 64; ++i) { e[i] = __expf(x[i] - m); l += e[i]; }
        l = wave_sum_bcast(l);
        const float inv = 1.f / l;
        #pragma unroll
        for (int i = 0; i < C_ / 64; ++i) wtf[(i * 64 + lane) * 4 + c] = e[i] * inv;
    }
    __syncthreads();

    // ---- phase 4: per-wave partial o over its 32 d-rows ----
    float4 acc[TC];
    #pragma unroll
    for (int c = 0; c < TC; ++c) acc[c] = make_float4(0.f, 0.f, 0.f, 0.f);

    {
        const float4* vp = (const float4*)(vbase + (size_t)(w * DPW) * S_) + lane;
        #pragma unroll 4
        for (int dd = 0; dd < DPW; ++dd) {
            const float4 vv = vp[dd * (S_ / 4)];
            const float4 ww = wtq[w * DPW + dd];   // uniform b128 broadcast
            acc[0].x += ww.x * vv.x; acc[0].y += ww.x * vv.y;
            acc[0].z += ww.x * vv.z; acc[0].w += ww.x * vv.w;
            acc[1].x += ww.y * vv.x; acc[1].y += ww.y * vv.y;
            acc[1].z += ww.y * vv.z; acc[1].w += ww.y * vv.w;
            acc[2].x += ww.z * vv.x; acc[2].y += ww.z * vv.y;
            acc[2].z += ww.z * vv.z; acc[2].w += ww.z * vv.w;
            acc[3].x += ww.w * vv.x; acc[3].y += ww.w * vv.y;
            acc[3].z += ww.w * vv.z; acc[3].w += ww.w * vv.w;
        }
    }
    #pragma unroll
    for (int c = 0; c < TC; ++c) accs[w][c][lane] = acc[c];
    __syncthreads();

    // ---- epilogue: sum 16 wave-partials, write output (waves 0..3) ----
    if (tid < TC * 64) {
        const int c  = tid >> 6;
        const int sq = tid & 63;
        float4 s = make_float4(0.f, 0.f, 0.f, 0.f);
        #pragma unroll
        for (int wv = 0; wv < NW; ++wv) {
            const float4 a = accs[wv][c][sq];
            s.x += a.x; s.y += a.y; s.z += a.z; s.w += a.w;
        }
        ((float4*)(out + ((size_t)n * C_ + c0 + c) * S_))[sq] = s;
    }
}

extern "C" void kernel_launch(void* const* d_in, const int* in_sizes, int n_in,
                              void* d_out, int out_size, void* d_ws, size_t ws_size,
                              hipStream_t stream) {
    const float* q = (const float*)d_in[0];
    const float* k = (const float*)d_in[1];
    const float* v = (const float*)d_in[2];
    float* out = (float*)d_out;

    laplace_attn_fused<<<dim3(N_ * (C_ / TC)), dim3(1024), 0, stream>>>(q, k, v, out);
}